// Round 7
// baseline (886.237 us; speedup 1.0000x reference)
//
#include <hip/hip_runtime.h>
#include <hip/hip_bf16.h>
#include <math.h>

// Problem constants
#define Bsz 2048
#define T1  9      // T-1
#define Hs  512
#define IN2 15

typedef __bf16 bf16x8 __attribute__((ext_vector_type(8)));
typedef float  f32x4  __attribute__((ext_vector_type(4)));
typedef __hip_bfloat16 bf16;

// ---------------------------------------------------------------------------
// Algebra (verified rounds 1-6):
//  * enc softmax over features invariant to (h@Wh+s@Ws) scalar => a1/a2
//    constant over time; Wh/Ws dead.
//  * dec attention: score = Xe.v + const(b), v = W2@W1x => beta/context
//    constant across decoder steps; rank-1 y_tilde term folded into epilogue.
// Precision: bf16x2 (A.W ~= Ahi.Whi + Ahi.Wlo), absmax 2e-3 vs 5.9e-3 budget.
// R3-5 lesson: whole-struct runtime select => scratch (654MB writes). Fixed by
// block-uniform SCALAR field selects (R6: 861us, writes back to 20MB).
// R6 counters: prep_v_k 68us (latency-serial GEMV) -> wave-per-output rewrite.
// lstm2_k latency-bound (MfmaUtil 22%, all pipes idle): 5 prefetch loads only
// covered by ~78cy MFMA -> DEPTH-2 register prefetch (A/B parity reg sets,
// loads issued 2 K-tiles ahead; compiler's per-reg vmcnt keeps newer parity's
// loads in flight across the barrier). 2-barrier schedule preserved.
// Weight layout n' = (j/16)*64 + g*16 + (j%16): a 64-wide wave n' window holds
// all 4 gates for 16 j's -> fully in-register gate epilogue.
// ---------------------------------------------------------------------------

#define BMT 64    // rows (batch) per block
#define BNP 128   // n' cols per block
#define LDK 40    // padded LDS row length in bf16 (32 data + 8 pad -> 80B)

struct GA {
  const bf16* Ahi;   // B x HG   activations (hi)
  const bf16* Axhi;  // B x 16   x-part for this t (enc) or null
  const bf16* Whi;   // 4HG x Kpad, n'-ordered
  const bf16* Wlo;
  const float* bsum; // 4HG, n'-ordered (bih+bhh)
  const float* wihp; // 4HG, n'-ordered rank-1 weights (dec) or null
  const float* ytp;  // rank-1 activation column y_tilde (dec) or null
  float* c;          // B x HG cell state (in/out)
  bf16* Hhi;         // B x HG h out
  float* hf;         // optional fp32 h out (Xe slice / final d) or null
  int hf_stride;
  int ytstride;
};

template<int HG, int KPAD, bool HAS_X, int ZD>
__global__ __launch_bounds__(256, 2)
void lstm2_k(GA a0, GA a1) {
  constexpr int KT = KPAD / 32;
  constexpr int GX = (4 * HG) / BNP;
  constexpr int GY = Bsz / BMT;       // 32
  constexpr int NWG = GX * GY * ZD;
  constexpr int Q = NWG / 8;

  __shared__ __align__(16) unsigned short As[BMT * LDK];
  __shared__ __align__(16) unsigned short Bh[BNP * LDK];
  __shared__ __align__(16) unsigned short Bl[BNP * LDK];

  const int tid = threadIdx.x;
  // bijective XCD swizzle (NWG % 8 == 0); mb fastest -> the 32-consecutive
  // blocks on one XCD share one weight n-panel in that XCD's L2.
  const int orig = blockIdx.x + GX * (blockIdx.y + GY * blockIdx.z);
  const int swz = (orig & 7) * Q + (orig >> 3);
  // ---- SCALAR field selects (block-uniform -> SGPR cselect, no scratch) ----
  const bool sel = (ZD == 2) && (swz >= GX * GY);
  const bf16* __restrict__ Ahi  = sel ? a1.Ahi  : a0.Ahi;
  const bf16* __restrict__ Axhi = sel ? a1.Axhi : a0.Axhi;
  const bf16* __restrict__ Whi  = sel ? a1.Whi  : a0.Whi;
  const bf16* __restrict__ Wlo  = sel ? a1.Wlo  : a0.Wlo;
  const float* __restrict__ bsum = sel ? a1.bsum : a0.bsum;
  const float* __restrict__ wihp = sel ? a1.wihp : a0.wihp;
  const float* __restrict__ ytp  = sel ? a1.ytp  : a0.ytp;
  float* __restrict__ cst = sel ? a1.c   : a0.c;
  bf16*  __restrict__ Hhi = sel ? a1.Hhi : a0.Hhi;
  float* __restrict__ hf  = sel ? a1.hf  : a0.hf;
  const int hf_stride = sel ? a1.hf_stride : a0.hf_stride;
  const int ytstride  = sel ? a1.ytstride  : a0.ytstride;

  const int rem = (ZD == 2) ? (swz & (GX * GY - 1)) : swz;
  const int nb = rem / GY;
  const int mb = rem % GY;
  const int m0 = mb * BMT, n0 = nb * BNP;

  // staging map: each thread owns one 8-elem k-chunk; A row ra, W rows ra, ra+64
  const int kcb = (tid & 3) * 8;
  const int ra = tid >> 2;   // 0..63

  auto stage_load = [&](int kt, uint4& r0, uint4& r1, uint4& r2, uint4& r3, uint4& r4) {
    const int ke = kt * 32 + kcb;
    if (!HAS_X || ke < HG) {
      r0 = *reinterpret_cast<const uint4*>(Ahi + (size_t)(m0 + ra) * HG + ke);
    } else if (ke < HG + 16) {
      r0 = *reinterpret_cast<const uint4*>(Axhi + (size_t)(m0 + ra) * 16 + (ke - HG));
    } else {
      r0.x = r0.y = r0.z = r0.w = 0u;
    }
    const size_t bg = (size_t)(n0 + ra) * KPAD + ke;
    r1 = *reinterpret_cast<const uint4*>(Whi + bg);
    r2 = *reinterpret_cast<const uint4*>(Whi + bg + (size_t)64 * KPAD);
    r3 = *reinterpret_cast<const uint4*>(Wlo + bg);
    r4 = *reinterpret_cast<const uint4*>(Wlo + bg + (size_t)64 * KPAD);
  };
  auto stage_write = [&](const uint4& r0, const uint4& r1, const uint4& r2,
                         const uint4& r3, const uint4& r4) {
    unsigned short* ap = &As[ra * LDK + kcb];
    *reinterpret_cast<uint4*>(ap) = r0;
    unsigned short* hp = &Bh[ra * LDK + kcb];
    *reinterpret_cast<uint4*>(hp) = r1;
    *reinterpret_cast<uint4*>(hp + 64 * LDK) = r2;
    unsigned short* lp = &Bl[ra * LDK + kcb];
    *reinterpret_cast<uint4*>(lp) = r3;
    *reinterpret_cast<uint4*>(lp + 64 * LDK) = r4;
  };

  const int lane = tid & 63;
  const int wv = tid >> 6;
  const int wr = wv >> 1, wc = wv & 1;  // 2x2 wave grid: 32 rows x 64 n'-cols each
  const int l15 = lane & 15;
  const int lk = (lane >> 4) * 8;

  const int aoff0 = (wr * 32 + l15) * LDK + lk;
  const int aoff1 = (wr * 32 + 16 + l15) * LDK + lk;
  const int boff0 = (wc * 64 + l15) * LDK + lk;
  const int boff1 = (wc * 64 + 16 + l15) * LDK + lk;
  const int boff2 = (wc * 64 + 32 + l15) * LDK + lk;
  const int boff3 = (wc * 64 + 48 + l15) * LDK + lk;

  f32x4 acc[2][4] = {};

  // depth-2 prefetch: parity-A and parity-B named register sets
  uint4 pa0, pa1, pa2, pa3, pa4;
  uint4 pb0, pb1, pb2, pb3, pb4;
  stage_load(0, pa0, pa1, pa2, pa3, pa4);
  if (KT > 1) stage_load(1, pb0, pb1, pb2, pb3, pb4);

  for (int kt = 0; kt < KT; ++kt) {
    __syncthreads();  // previous tile's frag reads complete
    if ((kt & 1) == 0) stage_write(pa0, pa1, pa2, pa3, pa4);
    else               stage_write(pb0, pb1, pb2, pb3, pb4);
    __syncthreads();  // tile ready

    bf16x8 ah0 = __builtin_bit_cast(bf16x8, *reinterpret_cast<const uint4*>(&As[aoff0]));
    bf16x8 ah1 = __builtin_bit_cast(bf16x8, *reinterpret_cast<const uint4*>(&As[aoff1]));
    if (kt + 2 < KT) {  // refill the parity just consumed, 2 tiles ahead
      if ((kt & 1) == 0) stage_load(kt + 2, pa0, pa1, pa2, pa3, pa4);
      else               stage_load(kt + 2, pb0, pb1, pb2, pb3, pb4);
    }
    const int boffs[4] = {boff0, boff1, boff2, boff3};
#pragma unroll
    for (int ni = 0; ni < 4; ++ni) {
      bf16x8 bhv = __builtin_bit_cast(bf16x8, *reinterpret_cast<const uint4*>(&Bh[boffs[ni]]));
      bf16x8 blv = __builtin_bit_cast(bf16x8, *reinterpret_cast<const uint4*>(&Bl[boffs[ni]]));
      acc[0][ni] = __builtin_amdgcn_mfma_f32_16x16x32_bf16(ah0, bhv, acc[0][ni], 0, 0, 0);
      acc[0][ni] = __builtin_amdgcn_mfma_f32_16x16x32_bf16(ah0, blv, acc[0][ni], 0, 0, 0);
      acc[1][ni] = __builtin_amdgcn_mfma_f32_16x16x32_bf16(ah1, bhv, acc[1][ni], 0, 0, 0);
      acc[1][ni] = __builtin_amdgcn_mfma_f32_16x16x32_bf16(ah1, blv, acc[1][ni], 0, 0, 0);
    }
  }

  // Epilogue: ni == gate g; j = nb*32 + wc*16 + l15
  const int j = nb * 32 + wc * 16 + l15;
  const int npb = nb * 128 + wc * 64 + l15;
  const float bs0 = bsum[npb], bs1 = bsum[npb + 16];
  const float bs2 = bsum[npb + 32], bs3 = bsum[npb + 48];
  float w0 = 0.f, w1 = 0.f, w2 = 0.f, w3 = 0.f;
  if (!HAS_X) {
    w0 = wihp[npb]; w1 = wihp[npb + 16];
    w2 = wihp[npb + 32]; w3 = wihp[npb + 48];
  }
#pragma unroll
  for (int mi = 0; mi < 2; ++mi) {
#pragma unroll
    for (int r = 0; r < 4; ++r) {
      const int rowl = wr * 32 + mi * 16 + (lane >> 4) * 4 + r;
      const size_t rowg = m0 + rowl;
      float gi = acc[mi][0][r] + bs0;
      float gf = acc[mi][1][r] + bs1;
      float gg = acc[mi][2][r] + bs2;
      float go = acc[mi][3][r] + bs3;
      if (!HAS_X) {
        const float yv = ytp[rowg * ytstride];
        gi += yv * w0; gf += yv * w1; gg += yv * w2; go += yv * w3;
      }
      const float i_ = 1.f / (1.f + __expf(-gi));
      const float f_ = 1.f / (1.f + __expf(-gf));
      const float tg = __expf(2.f * gg);
      const float g_ = (tg - 1.f) / (tg + 1.f);
      const float o_ = 1.f / (1.f + __expf(-go));
      const size_t idx = rowg * HG + j;
      const float cn = f_ * cst[idx] + i_ * g_;
      cst[idx] = cn;
      const float tc = __expf(2.f * cn);
      const float hn = o_ * (tc - 1.f) / (tc + 1.f);
      Hhi[idx] = __float2bfloat16(hn);
      if (hf) hf[rowg * hf_stride + j] = hn;
    }
  }
}

// Build composite weights in n'-interleaved order, split hi/lo; bsum; wihp.
// One thread per (np, 8-wide k chunk).
__global__ void build_w_k(const float* __restrict__ Whh, const float* __restrict__ Wih,
                          const float* __restrict__ bih, const float* __restrict__ bhh,
                          bf16* __restrict__ Whi, bf16* __restrict__ Wlo,
                          float* __restrict__ bsum, float* __restrict__ wihp,
                          int HG, int nx, int Kpad) {
  const int chunks = Kpad >> 3;
  const int idx = blockIdx.x * 256 + threadIdx.x;
  if (idx >= 4 * HG * chunks) return;
  const int np = idx / chunks;
  const int k0 = (idx - np * chunks) << 3;
  const int g = (np >> 4) & 3;
  const int jj = ((np >> 6) << 4) + (np & 15);
  const int norig = g * HG + jj;
  float v[8];
  if (k0 + 8 <= HG) {
    const float4* s = reinterpret_cast<const float4*>(Whh + (size_t)norig * HG + k0);
    float4 v0 = s[0], v1 = s[1];
    v[0] = v0.x; v[1] = v0.y; v[2] = v0.z; v[3] = v0.w;
    v[4] = v1.x; v[5] = v1.y; v[6] = v1.z; v[7] = v1.w;
  } else {
#pragma unroll
    for (int u = 0; u < 8; ++u) {
      const int k = k0 + u;
      v[u] = (k < HG) ? Whh[(size_t)norig * HG + k]
                      : ((k - HG < nx) ? Wih[(size_t)norig * nx + (k - HG)] : 0.f);
    }
  }
  unsigned short hh[8], ll[8];
#pragma unroll
  for (int u = 0; u < 8; ++u) {
    const bf16 h = __float2bfloat16(v[u]);
    const bf16 l = __float2bfloat16(v[u] - __bfloat162float(h));
    hh[u] = *reinterpret_cast<const unsigned short*>(&h);
    ll[u] = *reinterpret_cast<const unsigned short*>(&l);
  }
  const size_t off = (size_t)np * Kpad + k0;
  *reinterpret_cast<uint4*>((unsigned short*)Whi + off) = *reinterpret_cast<uint4*>(hh);
  *reinterpret_cast<uint4*>((unsigned short*)Wlo + off) = *reinterpret_cast<uint4*>(ll);
  if (k0 == 0) {
    bsum[np] = bih[norig] + bhh[norig];
    if (wihp) wihp[np] = Wih[norig];  // dec: Wih is (8H,1)
  }
}

// Per-batch encoder attention weights (time-invariant) -> x_tilde tables.
__global__ void prep_attn_k(const float* __restrict__ X, const float* __restrict__ yp,
                            const float* __restrict__ encW, const float* __restrict__ encb,
                            bf16* __restrict__ x1h, bf16* __restrict__ x2h) {
  const int b = blockIdx.x;
  const int tid = threadIdx.x;  // 64
  __shared__ float wf[T1], ypb[T1];
  __shared__ float s1[16], s2[IN2], e1[16], e2[IN2];
  if (tid < T1) {
    wf[tid] = encW[2 * Hs + tid];
    ypb[tid] = yp[(size_t)b * T1 + tid];
  }
  __syncthreads();
  const float bb = encb[0];
  if (tid < 16) {
    float acc = bb;
    for (int t = 0; t < T1; ++t) {
      float xv = (tid < IN2) ? X[(size_t)b * (T1 * IN2) + t * IN2 + tid] : ypb[t];
      acc += xv * wf[t];
    }
    s1[tid] = acc;
  } else if (tid < 16 + IN2) {
    const int k = tid - 16;
    float acc = bb;
    for (int t = 0; t < T1; ++t)
      acc += X[(size_t)b * (T1 * IN2) + t * IN2 + k] * ypb[t] * wf[t];
    s2[k] = acc;
  }
  __syncthreads();
  if (tid < 16) {
    float m = -1e30f;
    for (int k = 0; k < 16; ++k) m = fmaxf(m, s1[k]);
    e1[tid] = expf(s1[tid] - m);
  } else if (tid < 16 + IN2) {
    const int k = tid - 16;
    float m = -1e30f;
    for (int kk = 0; kk < IN2; ++kk) m = fmaxf(m, s2[kk]);
    e2[k] = expf(s2[k] - m);
  }
  __syncthreads();
  if (tid < 16) {
    float sum = 0.f;
    for (int k = 0; k < 16; ++k) sum += e1[k];
    const float a = e1[tid] / sum;
    for (int t = 0; t < T1; ++t) {
      float xv = (tid < IN2) ? X[(size_t)b * (T1 * IN2) + t * IN2 + tid] : ypb[t];
      x1h[((size_t)t * Bsz + b) * 16 + tid] = __float2bfloat16(a * xv);
    }
  } else if (tid < 16 + IN2) {
    const int k = tid - 16;
    float sum = 0.f;
    for (int kk = 0; kk < IN2; ++kk) sum += e2[kk];
    const float a = e2[k] / sum;
    for (int t = 0; t < T1; ++t)
      x2h[((size_t)t * Bsz + b) * 16 + k] =
          __float2bfloat16(a * X[(size_t)b * (T1 * IN2) + t * IN2 + k] * ypb[t]);
  } else if (tid == 31) {
    const bf16 z = __float2bfloat16(0.f);
    for (int t = 0; t < T1; ++t) x2h[((size_t)t * Bsz + b) * 16 + 15] = z;
  }
}

// v[dd] = sum_h dec_attn2_W[0,h] * dec_attn1_W[h, 4H+dd]
// Wave-per-output GEMV: grid 1024 x 64 threads, lane l sums 8 h's, shfl-reduce.
__global__ void prep_v_k(const float* __restrict__ A1W, const float* __restrict__ A2W,
                         float* __restrict__ v) {
  const int dd = blockIdx.x;      // 0..1023
  const int l = threadIdx.x;      // 0..63
  float acc = 0.f;
#pragma unroll
  for (int k = 0; k < 8; ++k) {
    const int h = l + 64 * k;
    acc += A2W[h] * A1W[(size_t)h * (6 * Hs) + 4 * Hs + dd];
  }
#pragma unroll
  for (int off = 32; off > 0; off >>= 1) acc += __shfl_down(acc, off);
  if (l == 0) v[dd] = acc;
}

// Decoder attention (step-invariant): softmax over t, context, y_tilde table.
__global__ void dec_ctx_k(const float* __restrict__ Xe, const float* __restrict__ v,
                          const float* __restrict__ yp, const float* __restrict__ fcW,
                          const float* __restrict__ fcb,
                          float* __restrict__ ctx, float* __restrict__ yt) {
  const int b = blockIdx.x;
  const int tid = threadIdx.x;  // 256
  const float* xb = Xe + (size_t)b * (T1 * 2 * Hs);
  float s[T1];
#pragma unroll
  for (int t = 0; t < T1; ++t) s[t] = 0.f;
  for (int dd = tid; dd < 2 * Hs; dd += 256) {
    const float vv = v[dd];
#pragma unroll
    for (int t = 0; t < T1; ++t) s[t] += xb[t * 2 * Hs + dd] * vv;
  }
  __shared__ float red[256];
  __shared__ float score[T1];
  for (int t = 0; t < T1; ++t) {
    red[tid] = s[t];
    __syncthreads();
    for (int off = 128; off > 0; off >>= 1) {
      if (tid < off) red[tid] += red[tid + off];
      __syncthreads();
    }
    if (tid == 0) score[t] = red[0];
    __syncthreads();
  }
  float mx = -1e30f;
#pragma unroll
  for (int t = 0; t < T1; ++t) mx = fmaxf(mx, score[t]);
  float e[T1];
  float sum = 0.f;
#pragma unroll
  for (int t = 0; t < T1; ++t) { e[t] = expf(score[t] - mx); sum += e[t]; }
  const float inv = 1.f / sum;
  float fcacc = 0.f;
  for (int dd = tid; dd < 2 * Hs; dd += 256) {
    float c = 0.f;
#pragma unroll
    for (int t = 0; t < T1; ++t) c += e[t] * xb[t * 2 * Hs + dd];
    c *= inv;
    ctx[(size_t)b * 2 * Hs + dd] = c;
    fcacc += c * fcW[dd];
  }
  red[tid] = fcacc;
  __syncthreads();
  for (int off = 128; off > 0; off >>= 1) {
    if (tid < off) red[tid] += red[tid + off];
    __syncthreads();
  }
  const float cf = red[0] + fcb[0];
  if (tid < T1) yt[(size_t)b * T1 + tid] = cf + yp[(size_t)b * T1 + tid] * fcW[2 * Hs];
}

__global__ void final_out_k(const float* __restrict__ dfin, const float* __restrict__ ctx,
                            const float* __restrict__ Wfin, const float* __restrict__ bfin,
                            float* __restrict__ out) {
  const int b = blockIdx.x;
  const int tid = threadIdx.x;  // 256
  float acc = 0.f;
  for (int jj = tid; jj < 2 * Hs; jj += 256) acc += dfin[(size_t)b * 2 * Hs + jj] * Wfin[jj];
  for (int jj = tid; jj < 2 * Hs; jj += 256) acc += ctx[(size_t)b * 2 * Hs + jj] * Wfin[2 * Hs + jj];
  __shared__ float red[256];
  red[tid] = acc;
  __syncthreads();
  for (int off = 128; off > 0; off >>= 1) {
    if (tid < off) red[tid] += red[tid + off];
    __syncthreads();
  }
  if (tid == 0) out[b] = red[0] + bfin[0];
}

extern "C" void kernel_launch(void* const* d_in, const int* in_sizes, int n_in,
                              void* d_out, int out_size, void* d_ws, size_t ws_size,
                              hipStream_t stream) {
  const float* X     = (const float*)d_in[0];
  const float* yp    = (const float*)d_in[1];
  const float* encW  = (const float*)d_in[2];
  const float* encb  = (const float*)d_in[3];
  const float* e0Wih = (const float*)d_in[4];
  const float* e0Whh = (const float*)d_in[5];
  const float* e0bih = (const float*)d_in[6];
  const float* e0bhh = (const float*)d_in[7];
  const float* e1Wih = (const float*)d_in[8];
  const float* e1Whh = (const float*)d_in[9];
  const float* e1bih = (const float*)d_in[10];
  const float* e1bhh = (const float*)d_in[11];
  const float* dA1W  = (const float*)d_in[12];
  const float* dA2W  = (const float*)d_in[14];
  const float* dWih  = (const float*)d_in[16];
  const float* dWhh  = (const float*)d_in[17];
  const float* dbih  = (const float*)d_in[18];
  const float* dbhh  = (const float*)d_in[19];
  const float* fcW   = (const float*)d_in[20];
  const float* fcb   = (const float*)d_in[21];
  const float* WfinW = (const float*)d_in[22];
  const float* Wfinb = (const float*)d_in[23];
  float* out = (float*)d_out;
  (void)in_sizes; (void)n_in; (void)out_size; (void)ws_size;

  char* wsb = (char*)d_ws;
  size_t off = 0;
  auto alloc = [&](size_t bytes) -> void* {
    void* p = wsb + off;
    off = (off + bytes + 255) & ~(size_t)255;
    return p;
  };
  const size_t BH  = (size_t)Bsz * Hs;
  const size_t BH2 = (size_t)Bsz * 2 * Hs;
  // ---- zero-init region (one memset per call) ----
  float* c1   = (float*)alloc(BH * 4);
  float* c2   = (float*)alloc(BH * 4);
  float* cdec = (float*)alloc(BH2 * 4);
  bf16* h1hi0 = (bf16*)alloc(BH * 2);
  bf16* h2hi0 = (bf16*)alloc(BH * 2);
  bf16* dhi0  = (bf16*)alloc(BH2 * 2);
  const size_t zero_bytes = off;
  // ---- rest ----
  bf16* h1hi1 = (bf16*)alloc(BH * 2);
  bf16* h2hi1 = (bf16*)alloc(BH * 2);
  bf16* dhi1  = (bf16*)alloc(BH2 * 2);
  bf16* W0hi  = (bf16*)alloc((size_t)2048 * 544 * 2);
  bf16* W0lo  = (bf16*)alloc((size_t)2048 * 544 * 2);
  bf16* W1hi  = (bf16*)alloc((size_t)2048 * 544 * 2);
  bf16* W1lo  = (bf16*)alloc((size_t)2048 * 544 * 2);
  bf16* Wdhi  = (bf16*)alloc((size_t)4096 * 1024 * 2);
  bf16* Wdlo  = (bf16*)alloc((size_t)4096 * 1024 * 2);
  float* bs0  = (float*)alloc(2048 * 4);
  float* bs1  = (float*)alloc(2048 * 4);
  float* bsd  = (float*)alloc(4096 * 4);
  float* wihp = (float*)alloc(4096 * 4);
  bf16* x1h   = (bf16*)alloc((size_t)T1 * Bsz * 16 * 2);
  bf16* x2h   = (bf16*)alloc((size_t)T1 * Bsz * 16 * 2);
  float* Xe   = (float*)alloc((size_t)Bsz * T1 * 2 * Hs * 4);
  float* dfp  = (float*)alloc(BH2 * 4);
  float* ctx  = (float*)alloc(BH2 * 4);
  float* vv   = (float*)alloc(2 * Hs * 4);
  float* yt   = (float*)alloc((size_t)Bsz * T1 * 4);

  hipMemsetAsync(d_ws, 0, zero_bytes, stream);

  build_w_k<<<(4 * Hs * (544 / 8) + 255) / 256, 256, 0, stream>>>(
      e0Whh, e0Wih, e0bih, e0bhh, W0hi, W0lo, bs0, nullptr, Hs, 16, 544);
  build_w_k<<<(4 * Hs * (544 / 8) + 255) / 256, 256, 0, stream>>>(
      e1Whh, e1Wih, e1bih, e1bhh, W1hi, W1lo, bs1, nullptr, Hs, 15, 544);
  build_w_k<<<(8 * Hs * (1024 / 8) + 255) / 256, 256, 0, stream>>>(
      dWhh, dWih, dbih, dbhh, Wdhi, Wdlo, bsd, wihp, 2 * Hs, 0, 1024);
  prep_attn_k<<<Bsz, 64, 0, stream>>>(X, yp, encW, encb, x1h, x2h);
  prep_v_k<<<2 * Hs, 64, 0, stream>>>(dA1W, dA2W, vv);

  // ---- encoder: 9 steps, both branches per launch ----
  bf16 *h1c = h1hi0, *h1n = h1hi1;
  bf16 *h2c = h2hi0, *h2n = h2hi1;
  for (int t = 0; t < T1; ++t) {
    GA a0{h1c, x1h + (size_t)t * Bsz * 16, W0hi, W0lo, bs0, nullptr, nullptr,
          c1, h1n, Xe + (size_t)t * 2 * Hs, T1 * 2 * Hs, 0};
    GA a1{h2c, x2h + (size_t)t * Bsz * 16, W1hi, W1lo, bs1, nullptr, nullptr,
          c2, h2n, Xe + (size_t)t * 2 * Hs + Hs, T1 * 2 * Hs, 0};
    dim3 grid((4 * Hs) / BNP, Bsz / BMT, 2);
    lstm2_k<Hs, 544, true, 2><<<grid, 256, 0, stream>>>(a0, a1);
    bf16* tp;
    tp = h1c; h1c = h1n; h1n = tp;
    tp = h2c; h2c = h2n; h2n = tp;
  }

  dec_ctx_k<<<Bsz, 256, 0, stream>>>(Xe, vv, yp, fcW, fcb, ctx, yt);

  // ---- decoder: 9 steps ----
  bf16 *dc = dhi0, *dn = dhi1;
  for (int t = 0; t < T1; ++t) {
    GA a0{dc, nullptr, Wdhi, Wdlo, bsd, wihp, yt + t,
          cdec, dn, (t == T1 - 1) ? dfp : nullptr, 2 * Hs, T1};
    dim3 grid((8 * Hs) / BNP, Bsz / BMT, 1);
    lstm2_k<2 * Hs, 1024, false, 1><<<grid, 256, 0, stream>>>(a0, a0);
    bf16* tp = dc; dc = dn; dn = tp;
  }

  final_out_k<<<Bsz, 256, 0, stream>>>(dfp, ctx, WfinW, Wfinb, out);
}

// Round 8
// 823.505 us; speedup vs baseline: 1.0762x; 1.0762x over previous
//
#include <hip/hip_runtime.h>
#include <hip/hip_bf16.h>
#include <math.h>

// Problem constants
#define Bsz 2048
#define T1  9      // T-1
#define Hs  512
#define IN2 15

typedef __bf16 bf16x8 __attribute__((ext_vector_type(8)));
typedef float  f32x4  __attribute__((ext_vector_type(4)));
typedef __hip_bfloat16 bf16;

// ---------------------------------------------------------------------------
// Algebra (verified rounds 1-7):
//  * enc softmax over features invariant to (h@Wh+s@Ws) scalar => a1/a2
//    constant over time; Wh/Ws dead.
//  * dec attention: score = Xe.v + const(b), v = W2@W1x => beta/context
//    constant across decoder steps; rank-1 y_tilde term folded into epilogue.
// Precision: bf16x2 (A.W ~= Ahi.Whi + Ahi.Wlo), absmax 2e-3 vs 5.9e-3 budget.
// R3-5: whole-struct runtime select => scratch. Fixed via scalar field selects.
// R7: depth-2 parity prefetch REGRESSED (VALU addr overhead) -> depth-1 (R6).
// R6/R7 counters: SQ_LDS_BANK_CONFLICT 10.5M/dispatch; kernel is LDS-BW-bound
// (7.9MB/CU/dispatch ~38us + 17us conflicts ~= 55 of 61us). THIS ROUND:
// LDK 40->32 + XOR swizzle  off = (row*32+chunk) ^ ((row&7)<<3)  on BOTH
// ds_write and ds_read (same involution, G21). Paper-verified: every 8-lane
// phase of write and read patterns hits 8 distinct bank-quads -> conflict-free.
// Weight layout n' = (j/16)*64 + g*16 + (j%16): a 64-wide wave n' window holds
// all 4 gates for 16 j's -> fully in-register gate epilogue.
// ---------------------------------------------------------------------------

#define BMT 64    // rows (batch) per block
#define BNP 128   // n' cols per block

struct GA {
  const bf16* Ahi;   // B x HG   activations (hi)
  const bf16* Axhi;  // B x 16   x-part for this t (enc) or null
  const bf16* Whi;   // 4HG x Kpad, n'-ordered
  const bf16* Wlo;
  const float* bsum; // 4HG, n'-ordered (bih+bhh)
  const float* wihp; // 4HG, n'-ordered rank-1 weights (dec) or null
  const float* ytp;  // rank-1 activation column y_tilde (dec) or null
  float* c;          // B x HG cell state (in/out)
  bf16* Hhi;         // B x HG h out
  float* hf;         // optional fp32 h out (Xe slice / final d) or null
  int hf_stride;
  int ytstride;
};

template<int HG, int KPAD, bool HAS_X, int ZD>
__global__ __launch_bounds__(256, 2)
void lstm2_k(GA a0, GA a1) {
  constexpr int KT = KPAD / 32;
  constexpr int GX = (4 * HG) / BNP;
  constexpr int GY = Bsz / BMT;       // 32
  constexpr int NWG = GX * GY * ZD;
  constexpr int Q = NWG / 8;

  __shared__ __align__(16) unsigned short As[BMT * 32];
  __shared__ __align__(16) unsigned short Bh[BNP * 32];
  __shared__ __align__(16) unsigned short Bl[BNP * 32];

  const int tid = threadIdx.x;
  // bijective XCD swizzle (NWG % 8 == 0); mb fastest -> the 32-consecutive
  // blocks on one XCD share one weight n-panel in that XCD's L2.
  const int orig = blockIdx.x + GX * (blockIdx.y + GY * blockIdx.z);
  const int swz = (orig & 7) * Q + (orig >> 3);
  // ---- SCALAR field selects (block-uniform -> SGPR cselect, no scratch) ----
  const bool sel = (ZD == 2) && (swz >= GX * GY);
  const bf16* __restrict__ Ahi  = sel ? a1.Ahi  : a0.Ahi;
  const bf16* __restrict__ Axhi = sel ? a1.Axhi : a0.Axhi;
  const bf16* __restrict__ Whi  = sel ? a1.Whi  : a0.Whi;
  const bf16* __restrict__ Wlo  = sel ? a1.Wlo  : a0.Wlo;
  const float* __restrict__ bsum = sel ? a1.bsum : a0.bsum;
  const float* __restrict__ wihp = sel ? a1.wihp : a0.wihp;
  const float* __restrict__ ytp  = sel ? a1.ytp  : a0.ytp;
  float* __restrict__ cst = sel ? a1.c   : a0.c;
  bf16*  __restrict__ Hhi = sel ? a1.Hhi : a0.Hhi;
  float* __restrict__ hf  = sel ? a1.hf  : a0.hf;
  const int hf_stride = sel ? a1.hf_stride : a0.hf_stride;
  const int ytstride  = sel ? a1.ytstride  : a0.ytstride;

  const int rem = (ZD == 2) ? (swz & (GX * GY - 1)) : swz;
  const int nb = rem / GY;
  const int mb = rem % GY;
  const int m0 = mb * BMT, n0 = nb * BNP;

  // staging map: each thread owns one 8-elem k-chunk; A row ra, W rows ra, ra+64
  const int kcb = (tid & 3) * 8;
  const int ra = tid >> 2;   // 0..63

  uint4 s0, s1, s2, s3, s4;   // named staging regs
  auto stage_load = [&](int kt) {
    const int ke = kt * 32 + kcb;
    if (!HAS_X || ke < HG) {
      s0 = *reinterpret_cast<const uint4*>(Ahi + (size_t)(m0 + ra) * HG + ke);
    } else if (ke < HG + 16) {
      s0 = *reinterpret_cast<const uint4*>(Axhi + (size_t)(m0 + ra) * 16 + (ke - HG));
    } else {
      s0.x = s0.y = s0.z = s0.w = 0u;
    }
    const size_t bg = (size_t)(n0 + ra) * KPAD + ke;
    s1 = *reinterpret_cast<const uint4*>(Whi + bg);
    s2 = *reinterpret_cast<const uint4*>(Whi + bg + (size_t)64 * KPAD);
    s3 = *reinterpret_cast<const uint4*>(Wlo + bg);
    s4 = *reinterpret_cast<const uint4*>(Wlo + bg + (size_t)64 * KPAD);
  };
  // XOR-swizzled write offsets (16B-chunk granularity); (ra+64)&7 == ra&7
  const int wofA = (ra * 32 + kcb) ^ ((ra & 7) << 3);
  const int wofB = wofA + 64 * 32;

  const int lane = tid & 63;
  const int wv = tid >> 6;
  const int wr = wv >> 1, wc = wv & 1;  // 2x2 wave grid: 32 rows x 64 n'-cols each
  const int l15 = lane & 15;
  const int lk = (lane >> 4) * 8;

  // XOR-swizzled read offsets; +16 rows = +512 elems (XOR bits untouched)
  const int rswz = (l15 & 7) << 3;
  const int aoff0 = (((wr * 32 + l15) * 32) + lk) ^ rswz;
  const int aoff1 = aoff0 + 512;
  const int boff0 = (((wc * 64 + l15) * 32) + lk) ^ rswz;
  const int boff1 = boff0 + 512;
  const int boff2 = boff0 + 1024;
  const int boff3 = boff0 + 1536;

  f32x4 acc[2][4] = {};

  stage_load(0);
  for (int kt = 0; kt < KT; ++kt) {
    __syncthreads();  // previous tile's frag reads complete
    {
      *reinterpret_cast<uint4*>(&As[wofA]) = s0;
      *reinterpret_cast<uint4*>(&Bh[wofA]) = s1;
      *reinterpret_cast<uint4*>(&Bh[wofB]) = s2;
      *reinterpret_cast<uint4*>(&Bl[wofA]) = s3;
      *reinterpret_cast<uint4*>(&Bl[wofB]) = s4;
    }
    __syncthreads();  // tile ready

    bf16x8 ah0 = __builtin_bit_cast(bf16x8, *reinterpret_cast<const uint4*>(&As[aoff0]));
    bf16x8 ah1 = __builtin_bit_cast(bf16x8, *reinterpret_cast<const uint4*>(&As[aoff1]));
    if (kt + 1 < KT) stage_load(kt + 1);  // overlap next-tile globals with MFMA
    const int boffs[4] = {boff0, boff1, boff2, boff3};
#pragma unroll
    for (int ni = 0; ni < 4; ++ni) {
      bf16x8 bhv = __builtin_bit_cast(bf16x8, *reinterpret_cast<const uint4*>(&Bh[boffs[ni]]));
      bf16x8 blv = __builtin_bit_cast(bf16x8, *reinterpret_cast<const uint4*>(&Bl[boffs[ni]]));
      acc[0][ni] = __builtin_amdgcn_mfma_f32_16x16x32_bf16(ah0, bhv, acc[0][ni], 0, 0, 0);
      acc[0][ni] = __builtin_amdgcn_mfma_f32_16x16x32_bf16(ah0, blv, acc[0][ni], 0, 0, 0);
      acc[1][ni] = __builtin_amdgcn_mfma_f32_16x16x32_bf16(ah1, bhv, acc[1][ni], 0, 0, 0);
      acc[1][ni] = __builtin_amdgcn_mfma_f32_16x16x32_bf16(ah1, blv, acc[1][ni], 0, 0, 0);
    }
  }

  // Epilogue: ni == gate g; j = nb*32 + wc*16 + l15
  const int j = nb * 32 + wc * 16 + l15;
  const int npb = nb * 128 + wc * 64 + l15;
  const float bs0 = bsum[npb], bs1 = bsum[npb + 16];
  const float bs2 = bsum[npb + 32], bs3 = bsum[npb + 48];
  float w0 = 0.f, w1 = 0.f, w2 = 0.f, w3 = 0.f;
  if (!HAS_X) {
    w0 = wihp[npb]; w1 = wihp[npb + 16];
    w2 = wihp[npb + 32]; w3 = wihp[npb + 48];
  }
#pragma unroll
  for (int mi = 0; mi < 2; ++mi) {
#pragma unroll
    for (int r = 0; r < 4; ++r) {
      const int rowl = wr * 32 + mi * 16 + (lane >> 4) * 4 + r;
      const size_t rowg = m0 + rowl;
      float gi = acc[mi][0][r] + bs0;
      float gf = acc[mi][1][r] + bs1;
      float gg = acc[mi][2][r] + bs2;
      float go = acc[mi][3][r] + bs3;
      if (!HAS_X) {
        const float yv = ytp[rowg * ytstride];
        gi += yv * w0; gf += yv * w1; gg += yv * w2; go += yv * w3;
      }
      const float i_ = 1.f / (1.f + __expf(-gi));
      const float f_ = 1.f / (1.f + __expf(-gf));
      const float tg = __expf(2.f * gg);
      const float g_ = (tg - 1.f) / (tg + 1.f);
      const float o_ = 1.f / (1.f + __expf(-go));
      const size_t idx = rowg * HG + j;
      const float cn = f_ * cst[idx] + i_ * g_;
      cst[idx] = cn;
      const float tc = __expf(2.f * cn);
      const float hn = o_ * (tc - 1.f) / (tc + 1.f);
      Hhi[idx] = __float2bfloat16(hn);
      if (hf) hf[rowg * hf_stride + j] = hn;
    }
  }
}

// Build composite weights in n'-interleaved order, split hi/lo; bsum; wihp.
// One thread per (np, 8-wide k chunk).
__global__ void build_w_k(const float* __restrict__ Whh, const float* __restrict__ Wih,
                          const float* __restrict__ bih, const float* __restrict__ bhh,
                          bf16* __restrict__ Whi, bf16* __restrict__ Wlo,
                          float* __restrict__ bsum, float* __restrict__ wihp,
                          int HG, int nx, int Kpad) {
  const int chunks = Kpad >> 3;
  const int idx = blockIdx.x * 256 + threadIdx.x;
  if (idx >= 4 * HG * chunks) return;
  const int np = idx / chunks;
  const int k0 = (idx - np * chunks) << 3;
  const int g = (np >> 4) & 3;
  const int jj = ((np >> 6) << 4) + (np & 15);
  const int norig = g * HG + jj;
  float v[8];
  if (k0 + 8 <= HG) {
    const float4* s = reinterpret_cast<const float4*>(Whh + (size_t)norig * HG + k0);
    float4 v0 = s[0], v1 = s[1];
    v[0] = v0.x; v[1] = v0.y; v[2] = v0.z; v[3] = v0.w;
    v[4] = v1.x; v[5] = v1.y; v[6] = v1.z; v[7] = v1.w;
  } else {
#pragma unroll
    for (int u = 0; u < 8; ++u) {
      const int k = k0 + u;
      v[u] = (k < HG) ? Whh[(size_t)norig * HG + k]
                      : ((k - HG < nx) ? Wih[(size_t)norig * nx + (k - HG)] : 0.f);
    }
  }
  unsigned short hh[8], ll[8];
#pragma unroll
  for (int u = 0; u < 8; ++u) {
    const bf16 h = __float2bfloat16(v[u]);
    const bf16 l = __float2bfloat16(v[u] - __bfloat162float(h));
    hh[u] = *reinterpret_cast<const unsigned short*>(&h);
    ll[u] = *reinterpret_cast<const unsigned short*>(&l);
  }
  const size_t off = (size_t)np * Kpad + k0;
  *reinterpret_cast<uint4*>((unsigned short*)Whi + off) = *reinterpret_cast<uint4*>(hh);
  *reinterpret_cast<uint4*>((unsigned short*)Wlo + off) = *reinterpret_cast<uint4*>(ll);
  if (k0 == 0) {
    bsum[np] = bih[norig] + bhh[norig];
    if (wihp) wihp[np] = Wih[norig];  // dec: Wih is (8H,1)
  }
}

// Per-batch encoder attention weights (time-invariant) -> x_tilde tables.
__global__ void prep_attn_k(const float* __restrict__ X, const float* __restrict__ yp,
                            const float* __restrict__ encW, const float* __restrict__ encb,
                            bf16* __restrict__ x1h, bf16* __restrict__ x2h) {
  const int b = blockIdx.x;
  const int tid = threadIdx.x;  // 64
  __shared__ float wf[T1], ypb[T1];
  __shared__ float s1[16], s2[IN2], e1[16], e2[IN2];
  if (tid < T1) {
    wf[tid] = encW[2 * Hs + tid];
    ypb[tid] = yp[(size_t)b * T1 + tid];
  }
  __syncthreads();
  const float bb = encb[0];
  if (tid < 16) {
    float acc = bb;
    for (int t = 0; t < T1; ++t) {
      float xv = (tid < IN2) ? X[(size_t)b * (T1 * IN2) + t * IN2 + tid] : ypb[t];
      acc += xv * wf[t];
    }
    s1[tid] = acc;
  } else if (tid < 16 + IN2) {
    const int k = tid - 16;
    float acc = bb;
    for (int t = 0; t < T1; ++t)
      acc += X[(size_t)b * (T1 * IN2) + t * IN2 + k] * ypb[t] * wf[t];
    s2[k] = acc;
  }
  __syncthreads();
  if (tid < 16) {
    float m = -1e30f;
    for (int k = 0; k < 16; ++k) m = fmaxf(m, s1[k]);
    e1[tid] = expf(s1[tid] - m);
  } else if (tid < 16 + IN2) {
    const int k = tid - 16;
    float m = -1e30f;
    for (int kk = 0; kk < IN2; ++kk) m = fmaxf(m, s2[kk]);
    e2[k] = expf(s2[k] - m);
  }
  __syncthreads();
  if (tid < 16) {
    float sum = 0.f;
    for (int k = 0; k < 16; ++k) sum += e1[k];
    const float a = e1[tid] / sum;
    for (int t = 0; t < T1; ++t) {
      float xv = (tid < IN2) ? X[(size_t)b * (T1 * IN2) + t * IN2 + tid] : ypb[t];
      x1h[((size_t)t * Bsz + b) * 16 + tid] = __float2bfloat16(a * xv);
    }
  } else if (tid < 16 + IN2) {
    const int k = tid - 16;
    float sum = 0.f;
    for (int kk = 0; kk < IN2; ++kk) sum += e2[kk];
    const float a = e2[k] / sum;
    for (int t = 0; t < T1; ++t)
      x2h[((size_t)t * Bsz + b) * 16 + k] =
          __float2bfloat16(a * X[(size_t)b * (T1 * IN2) + t * IN2 + k] * ypb[t]);
  } else if (tid == 31) {
    const bf16 z = __float2bfloat16(0.f);
    for (int t = 0; t < T1; ++t) x2h[((size_t)t * Bsz + b) * 16 + 15] = z;
  }
}

// v[dd] = sum_h dec_attn2_W[0,h] * dec_attn1_W[h, 4H+dd]
// Wave-per-output GEMV: grid 1024 x 64 threads, lane l sums 8 h's, shfl-reduce.
__global__ void prep_v_k(const float* __restrict__ A1W, const float* __restrict__ A2W,
                         float* __restrict__ v) {
  const int dd = blockIdx.x;      // 0..1023
  const int l = threadIdx.x;      // 0..63
  float acc = 0.f;
#pragma unroll
  for (int k = 0; k < 8; ++k) {
    const int h = l + 64 * k;
    acc += A2W[h] * A1W[(size_t)h * (6 * Hs) + 4 * Hs + dd];
  }
#pragma unroll
  for (int off = 32; off > 0; off >>= 1) acc += __shfl_down(acc, off);
  if (l == 0) v[dd] = acc;
}

// Decoder attention (step-invariant): softmax over t, context, y_tilde table.
__global__ void dec_ctx_k(const float* __restrict__ Xe, const float* __restrict__ v,
                          const float* __restrict__ yp, const float* __restrict__ fcW,
                          const float* __restrict__ fcb,
                          float* __restrict__ ctx, float* __restrict__ yt) {
  const int b = blockIdx.x;
  const int tid = threadIdx.x;  // 256
  const float* xb = Xe + (size_t)b * (T1 * 2 * Hs);
  float s[T1];
#pragma unroll
  for (int t = 0; t < T1; ++t) s[t] = 0.f;
  for (int dd = tid; dd < 2 * Hs; dd += 256) {
    const float vv = v[dd];
#pragma unroll
    for (int t = 0; t < T1; ++t) s[t] += xb[t * 2 * Hs + dd] * vv;
  }
  __shared__ float red[256];
  __shared__ float score[T1];
  for (int t = 0; t < T1; ++t) {
    red[tid] = s[t];
    __syncthreads();
    for (int off = 128; off > 0; off >>= 1) {
      if (tid < off) red[tid] += red[tid + off];
      __syncthreads();
    }
    if (tid == 0) score[t] = red[0];
    __syncthreads();
  }
  float mx = -1e30f;
#pragma unroll
  for (int t = 0; t < T1; ++t) mx = fmaxf(mx, score[t]);
  float e[T1];
  float sum = 0.f;
#pragma unroll
  for (int t = 0; t < T1; ++t) { e[t] = expf(score[t] - mx); sum += e[t]; }
  const float inv = 1.f / sum;
  float fcacc = 0.f;
  for (int dd = tid; dd < 2 * Hs; dd += 256) {
    float c = 0.f;
#pragma unroll
    for (int t = 0; t < T1; ++t) c += e[t] * xb[t * 2 * Hs + dd];
    c *= inv;
    ctx[(size_t)b * 2 * Hs + dd] = c;
    fcacc += c * fcW[dd];
  }
  red[tid] = fcacc;
  __syncthreads();
  for (int off = 128; off > 0; off >>= 1) {
    if (tid < off) red[tid] += red[tid + off];
    __syncthreads();
  }
  const float cf = red[0] + fcb[0];
  if (tid < T1) yt[(size_t)b * T1 + tid] = cf + yp[(size_t)b * T1 + tid] * fcW[2 * Hs];
}

__global__ void final_out_k(const float* __restrict__ dfin, const float* __restrict__ ctx,
                            const float* __restrict__ Wfin, const float* __restrict__ bfin,
                            float* __restrict__ out) {
  const int b = blockIdx.x;
  const int tid = threadIdx.x;  // 256
  float acc = 0.f;
  for (int jj = tid; jj < 2 * Hs; jj += 256) acc += dfin[(size_t)b * 2 * Hs + jj] * Wfin[jj];
  for (int jj = tid; jj < 2 * Hs; jj += 256) acc += ctx[(size_t)b * 2 * Hs + jj] * Wfin[2 * Hs + jj];
  __shared__ float red[256];
  red[tid] = acc;
  __syncthreads();
  for (int off = 128; off > 0; off >>= 1) {
    if (tid < off) red[tid] += red[tid + off];
    __syncthreads();
  }
  if (tid == 0) out[b] = red[0] + bfin[0];
}

extern "C" void kernel_launch(void* const* d_in, const int* in_sizes, int n_in,
                              void* d_out, int out_size, void* d_ws, size_t ws_size,
                              hipStream_t stream) {
  const float* X     = (const float*)d_in[0];
  const float* yp    = (const float*)d_in[1];
  const float* encW  = (const float*)d_in[2];
  const float* encb  = (const float*)d_in[3];
  const float* e0Wih = (const float*)d_in[4];
  const float* e0Whh = (const float*)d_in[5];
  const float* e0bih = (const float*)d_in[6];
  const float* e0bhh = (const float*)d_in[7];
  const float* e1Wih = (const float*)d_in[8];
  const float* e1Whh = (const float*)d_in[9];
  const float* e1bih = (const float*)d_in[10];
  const float* e1bhh = (const float*)d_in[11];
  const float* dA1W  = (const float*)d_in[12];
  const float* dA2W  = (const float*)d_in[14];
  const float* dWih  = (const float*)d_in[16];
  const float* dWhh  = (const float*)d_in[17];
  const float* dbih  = (const float*)d_in[18];
  const float* dbhh  = (const float*)d_in[19];
  const float* fcW   = (const float*)d_in[20];
  const float* fcb   = (const float*)d_in[21];
  const float* WfinW = (const float*)d_in[22];
  const float* Wfinb = (const float*)d_in[23];
  float* out = (float*)d_out;
  (void)in_sizes; (void)n_in; (void)out_size; (void)ws_size;

  char* wsb = (char*)d_ws;
  size_t off = 0;
  auto alloc = [&](size_t bytes) -> void* {
    void* p = wsb + off;
    off = (off + bytes + 255) & ~(size_t)255;
    return p;
  };
  const size_t BH  = (size_t)Bsz * Hs;
  const size_t BH2 = (size_t)Bsz * 2 * Hs;
  // ---- zero-init region (one memset per call) ----
  float* c1   = (float*)alloc(BH * 4);
  float* c2   = (float*)alloc(BH * 4);
  float* cdec = (float*)alloc(BH2 * 4);
  bf16* h1hi0 = (bf16*)alloc(BH * 2);
  bf16* h2hi0 = (bf16*)alloc(BH * 2);
  bf16* dhi0  = (bf16*)alloc(BH2 * 2);
  const size_t zero_bytes = off;
  // ---- rest ----
  bf16* h1hi1 = (bf16*)alloc(BH * 2);
  bf16* h2hi1 = (bf16*)alloc(BH * 2);
  bf16* dhi1  = (bf16*)alloc(BH2 * 2);
  bf16* W0hi  = (bf16*)alloc((size_t)2048 * 544 * 2);
  bf16* W0lo  = (bf16*)alloc((size_t)2048 * 544 * 2);
  bf16* W1hi  = (bf16*)alloc((size_t)2048 * 544 * 2);
  bf16* W1lo  = (bf16*)alloc((size_t)2048 * 544 * 2);
  bf16* Wdhi  = (bf16*)alloc((size_t)4096 * 1024 * 2);
  bf16* Wdlo  = (bf16*)alloc((size_t)4096 * 1024 * 2);
  float* bs0  = (float*)alloc(2048 * 4);
  float* bs1  = (float*)alloc(2048 * 4);
  float* bsd  = (float*)alloc(4096 * 4);
  float* wihp = (float*)alloc(4096 * 4);
  bf16* x1h   = (bf16*)alloc((size_t)T1 * Bsz * 16 * 2);
  bf16* x2h   = (bf16*)alloc((size_t)T1 * Bsz * 16 * 2);
  float* Xe   = (float*)alloc((size_t)Bsz * T1 * 2 * Hs * 4);
  float* dfp  = (float*)alloc(BH2 * 4);
  float* ctx  = (float*)alloc(BH2 * 4);
  float* vv   = (float*)alloc(2 * Hs * 4);
  float* yt   = (float*)alloc((size_t)Bsz * T1 * 4);

  hipMemsetAsync(d_ws, 0, zero_bytes, stream);

  build_w_k<<<(4 * Hs * (544 / 8) + 255) / 256, 256, 0, stream>>>(
      e0Whh, e0Wih, e0bih, e0bhh, W0hi, W0lo, bs0, nullptr, Hs, 16, 544);
  build_w_k<<<(4 * Hs * (544 / 8) + 255) / 256, 256, 0, stream>>>(
      e1Whh, e1Wih, e1bih, e1bhh, W1hi, W1lo, bs1, nullptr, Hs, 15, 544);
  build_w_k<<<(8 * Hs * (1024 / 8) + 255) / 256, 256, 0, stream>>>(
      dWhh, dWih, dbih, dbhh, Wdhi, Wdlo, bsd, wihp, 2 * Hs, 0, 1024);
  prep_attn_k<<<Bsz, 64, 0, stream>>>(X, yp, encW, encb, x1h, x2h);
  prep_v_k<<<2 * Hs, 64, 0, stream>>>(dA1W, dA2W, vv);

  // ---- encoder: 9 steps, both branches per launch ----
  bf16 *h1c = h1hi0, *h1n = h1hi1;
  bf16 *h2c = h2hi0, *h2n = h2hi1;
  for (int t = 0; t < T1; ++t) {
    GA a0{h1c, x1h + (size_t)t * Bsz * 16, W0hi, W0lo, bs0, nullptr, nullptr,
          c1, h1n, Xe + (size_t)t * 2 * Hs, T1 * 2 * Hs, 0};
    GA a1{h2c, x2h + (size_t)t * Bsz * 16, W1hi, W1lo, bs1, nullptr, nullptr,
          c2, h2n, Xe + (size_t)t * 2 * Hs + Hs, T1 * 2 * Hs, 0};
    dim3 grid((4 * Hs) / BNP, Bsz / BMT, 2);
    lstm2_k<Hs, 544, true, 2><<<grid, 256, 0, stream>>>(a0, a1);
    bf16* tp;
    tp = h1c; h1c = h1n; h1n = tp;
    tp = h2c; h2c = h2n; h2n = tp;
  }

  dec_ctx_k<<<Bsz, 256, 0, stream>>>(Xe, vv, yp, fcW, fcb, ctx, yt);

  // ---- decoder: 9 steps ----
  bf16 *dc = dhi0, *dn = dhi1;
  for (int t = 0; t < T1; ++t) {
    GA a0{dc, nullptr, Wdhi, Wdlo, bsd, wihp, yt + t,
          cdec, dn, (t == T1 - 1) ? dfp : nullptr, 2 * Hs, T1};
    dim3 grid((8 * Hs) / BNP, Bsz / BMT, 1);
    lstm2_k<2 * Hs, 1024, false, 1><<<grid, 256, 0, stream>>>(a0, a0);
    bf16* tp = dc; dc = dn; dn = tp;
  }

  final_out_k<<<Bsz, 256, 0, stream>>>(dfp, ctx, WfinW, Wfinb, out);
}

// Round 9
// 734.696 us; speedup vs baseline: 1.2063x; 1.1209x over previous
//
#include <hip/hip_runtime.h>
#include <hip/hip_bf16.h>
#include <math.h>

// Problem constants
#define Bsz 2048
#define T1  9      // T-1
#define Hs  512
#define IN2 15

typedef __bf16 bf16x8 __attribute__((ext_vector_type(8)));
typedef float  f32x4  __attribute__((ext_vector_type(4)));
typedef __hip_bfloat16 bf16;

// ---------------------------------------------------------------------------
// Algebra (verified rounds 1-8):
//  * enc softmax over features invariant to (h@Wh+s@Ws) scalar => a1/a2
//    constant over time; Wh/Ws dead.
//  * dec attention: score = Xe.v + const(b), v = W2@W1x => beta/context
//    constant across decoder steps; rank-1 y_tilde term folded into epilogue.
// Precision: bf16x2 (A.W ~= Ahi.Whi + Ahi.Wlo), absmax 2e-3 vs 5.9e-3 budget.
// R3-5: whole-struct runtime select => scratch; fixed via scalar field selects.
// R7: depth-2 parity prefetch regressed -> depth-1. R8: XOR swizzle halved
// conflicts (10.5M->5.2M), 59.4us decoder; model says LDS-TRAFFIC-bound
// (7.9MB/CU ~38us >> MFMA 13.8us). Per-output LDS reads ~ (R/16+C/8)/(R*C):
// 32x64 waves carry 1.67x the B-frag traffic of 64x64 waves. THIS ROUND:
// BMT 64->128 (2x2 waves of 64x64, R2 geometry) => per-CU LDS 4.7MB (-40%).
// Occupancy 2 blocks/CU (grid-limited) - R2 proved structure at 68us/3-term.
// Weight layout n' = (j/16)*64 + g*16 + (j%16): a 64-wide wave n' window holds
// all 4 gates for 16 j's -> fully in-register gate epilogue.
// ---------------------------------------------------------------------------

#define BMT 128   // rows (batch) per block
#define BNP 128   // n' cols per block

struct GA {
  const bf16* Ahi;   // B x HG   activations (hi)
  const bf16* Axhi;  // B x 16   x-part for this t (enc) or null
  const bf16* Whi;   // 4HG x Kpad, n'-ordered
  const bf16* Wlo;
  const float* bsum; // 4HG, n'-ordered (bih+bhh)
  const float* wihp; // 4HG, n'-ordered rank-1 weights (dec) or null
  const float* ytp;  // rank-1 activation column y_tilde (dec) or null
  float* c;          // B x HG cell state (in/out)
  bf16* Hhi;         // B x HG h out
  float* hf;         // optional fp32 h out (Xe slice / final d) or null
  int hf_stride;
  int ytstride;
};

template<int HG, int KPAD, bool HAS_X, int ZD>
__global__ __launch_bounds__(256, 2)
void lstm2_k(GA a0, GA a1) {
  constexpr int KT = KPAD / 32;
  constexpr int GX = (4 * HG) / BNP;
  constexpr int GY = Bsz / BMT;       // 16
  constexpr int NWG = GX * GY * ZD;
  constexpr int Q = NWG / 8;

  __shared__ __align__(16) unsigned short As[BMT * 32];
  __shared__ __align__(16) unsigned short Bh[BNP * 32];
  __shared__ __align__(16) unsigned short Bl[BNP * 32];

  const int tid = threadIdx.x;
  // bijective XCD swizzle (NWG % 8 == 0); mb fastest -> consecutive blocks on
  // one XCD share one weight n-panel in that XCD's L2.
  const int orig = blockIdx.x + GX * (blockIdx.y + GY * blockIdx.z);
  const int swz = (orig & 7) * Q + (orig >> 3);
  // ---- SCALAR field selects (block-uniform -> SGPR cselect, no scratch) ----
  const bool sel = (ZD == 2) && (swz >= GX * GY);
  const bf16* __restrict__ Ahi  = sel ? a1.Ahi  : a0.Ahi;
  const bf16* __restrict__ Axhi = sel ? a1.Axhi : a0.Axhi;
  const bf16* __restrict__ Whi  = sel ? a1.Whi  : a0.Whi;
  const bf16* __restrict__ Wlo  = sel ? a1.Wlo  : a0.Wlo;
  const float* __restrict__ bsum = sel ? a1.bsum : a0.bsum;
  const float* __restrict__ wihp = sel ? a1.wihp : a0.wihp;
  const float* __restrict__ ytp  = sel ? a1.ytp  : a0.ytp;
  float* __restrict__ cst = sel ? a1.c   : a0.c;
  bf16*  __restrict__ Hhi = sel ? a1.Hhi : a0.Hhi;
  float* __restrict__ hf  = sel ? a1.hf  : a0.hf;
  const int hf_stride = sel ? a1.hf_stride : a0.hf_stride;
  const int ytstride  = sel ? a1.ytstride  : a0.ytstride;

  const int rem = (ZD == 2) ? (swz & (GX * GY - 1)) : swz;
  const int nb = rem / GY;
  const int mb = rem % GY;
  const int m0 = mb * BMT, n0 = nb * BNP;

  // staging map: each thread owns one 8-elem k-chunk on rows ra and ra+64
  const int kcb = (tid & 3) * 8;
  const int ra = tid >> 2;   // 0..63

  uint4 s0, s1, s2, s3, s4, s5;   // named staging regs
  auto stage_load = [&](int kt) {
    const int ke = kt * 32 + kcb;
    if (!HAS_X || ke < HG) {
      const size_t ag = (size_t)(m0 + ra) * HG + ke;
      s0 = *reinterpret_cast<const uint4*>(Ahi + ag);
      s5 = *reinterpret_cast<const uint4*>(Ahi + ag + (size_t)64 * HG);
    } else if (ke < HG + 16) {
      s0 = *reinterpret_cast<const uint4*>(Axhi + (size_t)(m0 + ra) * 16 + (ke - HG));
      s5 = *reinterpret_cast<const uint4*>(Axhi + (size_t)(m0 + ra + 64) * 16 + (ke - HG));
    } else {
      s0.x = s0.y = s0.z = s0.w = 0u;
      s5 = s0;
    }
    const size_t bg = (size_t)(n0 + ra) * KPAD + ke;
    s1 = *reinterpret_cast<const uint4*>(Whi + bg);
    s2 = *reinterpret_cast<const uint4*>(Whi + bg + (size_t)64 * KPAD);
    s3 = *reinterpret_cast<const uint4*>(Wlo + bg);
    s4 = *reinterpret_cast<const uint4*>(Wlo + bg + (size_t)64 * KPAD);
  };
  // XOR-swizzled write offsets (16B-chunk granularity); (ra+64)&7 == ra&7
  const int wofA = (ra * 32 + kcb) ^ ((ra & 7) << 3);
  const int wofB = wofA + 64 * 32;

  const int lane = tid & 63;
  const int wv = tid >> 6;
  const int wr = wv >> 1, wc = wv & 1;  // 2x2 wave grid: 64 rows x 64 n'-cols each
  const int l15 = lane & 15;
  const int lk = (lane >> 4) * 8;

  // XOR-swizzled read offsets; +16 rows = +512 elems (XOR bits untouched)
  const int rswz = (l15 & 7) << 3;
  const int aoff0 = (((wr * 64 + l15) * 32) + lk) ^ rswz;
  const int boff0 = (((wc * 64 + l15) * 32) + lk) ^ rswz;

  f32x4 acc[4][4] = {};

  stage_load(0);
  for (int kt = 0; kt < KT; ++kt) {
    __syncthreads();  // previous tile's frag reads complete
    {
      *reinterpret_cast<uint4*>(&As[wofA]) = s0;
      *reinterpret_cast<uint4*>(&As[wofB]) = s5;
      *reinterpret_cast<uint4*>(&Bh[wofA]) = s1;
      *reinterpret_cast<uint4*>(&Bh[wofB]) = s2;
      *reinterpret_cast<uint4*>(&Bl[wofA]) = s3;
      *reinterpret_cast<uint4*>(&Bl[wofB]) = s4;
    }
    __syncthreads();  // tile ready

    bf16x8 ah[4];
#pragma unroll
    for (int mi = 0; mi < 4; ++mi)
      ah[mi] = __builtin_bit_cast(bf16x8,
                 *reinterpret_cast<const uint4*>(&As[aoff0 + mi * 512]));
    if (kt + 1 < KT) stage_load(kt + 1);  // overlap next-tile globals with MFMA
#pragma unroll
    for (int ni = 0; ni < 4; ++ni) {
      bf16x8 bhv = __builtin_bit_cast(bf16x8,
                     *reinterpret_cast<const uint4*>(&Bh[boff0 + ni * 512]));
      bf16x8 blv = __builtin_bit_cast(bf16x8,
                     *reinterpret_cast<const uint4*>(&Bl[boff0 + ni * 512]));
#pragma unroll
      for (int mi = 0; mi < 4; ++mi) {
        acc[mi][ni] = __builtin_amdgcn_mfma_f32_16x16x32_bf16(ah[mi], bhv, acc[mi][ni], 0, 0, 0);
        acc[mi][ni] = __builtin_amdgcn_mfma_f32_16x16x32_bf16(ah[mi], blv, acc[mi][ni], 0, 0, 0);
      }
    }
  }

  // Epilogue: ni == gate g; j = nb*32 + wc*16 + l15
  const int j = nb * 32 + wc * 16 + l15;
  const int npb = nb * 128 + wc * 64 + l15;
  const float bs0 = bsum[npb], bs1 = bsum[npb + 16];
  const float bs2 = bsum[npb + 32], bs3 = bsum[npb + 48];
  float w0 = 0.f, w1 = 0.f, w2 = 0.f, w3 = 0.f;
  if (!HAS_X) {
    w0 = wihp[npb]; w1 = wihp[npb + 16];
    w2 = wihp[npb + 32]; w3 = wihp[npb + 48];
  }
#pragma unroll
  for (int mi = 0; mi < 4; ++mi) {
#pragma unroll
    for (int r = 0; r < 4; ++r) {
      const int rowl = wr * 64 + mi * 16 + (lane >> 4) * 4 + r;
      const size_t rowg = m0 + rowl;
      float gi = acc[mi][0][r] + bs0;
      float gf = acc[mi][1][r] + bs1;
      float gg = acc[mi][2][r] + bs2;
      float go = acc[mi][3][r] + bs3;
      if (!HAS_X) {
        const float yv = ytp[rowg * ytstride];
        gi += yv * w0; gf += yv * w1; gg += yv * w2; go += yv * w3;
      }
      const float i_ = 1.f / (1.f + __expf(-gi));
      const float f_ = 1.f / (1.f + __expf(-gf));
      const float tg = __expf(2.f * gg);
      const float g_ = (tg - 1.f) / (tg + 1.f);
      const float o_ = 1.f / (1.f + __expf(-go));
      const size_t idx = rowg * HG + j;
      const float cn = f_ * cst[idx] + i_ * g_;
      cst[idx] = cn;
      const float tc = __expf(2.f * cn);
      const float hn = o_ * (tc - 1.f) / (tc + 1.f);
      Hhi[idx] = __float2bfloat16(hn);
      if (hf) hf[rowg * hf_stride + j] = hn;
    }
  }
}

// Build composite weights in n'-interleaved order, split hi/lo; bsum; wihp.
// One thread per (np, 8-wide k chunk).
__global__ void build_w_k(const float* __restrict__ Whh, const float* __restrict__ Wih,
                          const float* __restrict__ bih, const float* __restrict__ bhh,
                          bf16* __restrict__ Whi, bf16* __restrict__ Wlo,
                          float* __restrict__ bsum, float* __restrict__ wihp,
                          int HG, int nx, int Kpad) {
  const int chunks = Kpad >> 3;
  const int idx = blockIdx.x * 256 + threadIdx.x;
  if (idx >= 4 * HG * chunks) return;
  const int np = idx / chunks;
  const int k0 = (idx - np * chunks) << 3;
  const int g = (np >> 4) & 3;
  const int jj = ((np >> 6) << 4) + (np & 15);
  const int norig = g * HG + jj;
  float v[8];
  if (k0 + 8 <= HG) {
    const float4* s = reinterpret_cast<const float4*>(Whh + (size_t)norig * HG + k0);
    float4 v0 = s[0], v1 = s[1];
    v[0] = v0.x; v[1] = v0.y; v[2] = v0.z; v[3] = v0.w;
    v[4] = v1.x; v[5] = v1.y; v[6] = v1.z; v[7] = v1.w;
  } else {
#pragma unroll
    for (int u = 0; u < 8; ++u) {
      const int k = k0 + u;
      v[u] = (k < HG) ? Whh[(size_t)norig * HG + k]
                      : ((k - HG < nx) ? Wih[(size_t)norig * nx + (k - HG)] : 0.f);
    }
  }
  unsigned short hh[8], ll[8];
#pragma unroll
  for (int u = 0; u < 8; ++u) {
    const bf16 h = __float2bfloat16(v[u]);
    const bf16 l = __float2bfloat16(v[u] - __bfloat162float(h));
    hh[u] = *reinterpret_cast<const unsigned short*>(&h);
    ll[u] = *reinterpret_cast<const unsigned short*>(&l);
  }
  const size_t off = (size_t)np * Kpad + k0;
  *reinterpret_cast<uint4*>((unsigned short*)Whi + off) = *reinterpret_cast<uint4*>(hh);
  *reinterpret_cast<uint4*>((unsigned short*)Wlo + off) = *reinterpret_cast<uint4*>(ll);
  if (k0 == 0) {
    bsum[np] = bih[norig] + bhh[norig];
    if (wihp) wihp[np] = Wih[norig];  // dec: Wih is (8H,1)
  }
}

// Per-batch encoder attention weights (time-invariant) -> x_tilde tables.
__global__ void prep_attn_k(const float* __restrict__ X, const float* __restrict__ yp,
                            const float* __restrict__ encW, const float* __restrict__ encb,
                            bf16* __restrict__ x1h, bf16* __restrict__ x2h) {
  const int b = blockIdx.x;
  const int tid = threadIdx.x;  // 64
  __shared__ float wf[T1], ypb[T1];
  __shared__ float s1[16], s2[IN2], e1[16], e2[IN2];
  if (tid < T1) {
    wf[tid] = encW[2 * Hs + tid];
    ypb[tid] = yp[(size_t)b * T1 + tid];
  }
  __syncthreads();
  const float bb = encb[0];
  if (tid < 16) {
    float acc = bb;
    for (int t = 0; t < T1; ++t) {
      float xv = (tid < IN2) ? X[(size_t)b * (T1 * IN2) + t * IN2 + tid] : ypb[t];
      acc += xv * wf[t];
    }
    s1[tid] = acc;
  } else if (tid < 16 + IN2) {
    const int k = tid - 16;
    float acc = bb;
    for (int t = 0; t < T1; ++t)
      acc += X[(size_t)b * (T1 * IN2) + t * IN2 + k] * ypb[t] * wf[t];
    s2[k] = acc;
  }
  __syncthreads();
  if (tid < 16) {
    float m = -1e30f;
    for (int k = 0; k < 16; ++k) m = fmaxf(m, s1[k]);
    e1[tid] = expf(s1[tid] - m);
  } else if (tid < 16 + IN2) {
    const int k = tid - 16;
    float m = -1e30f;
    for (int kk = 0; kk < IN2; ++kk) m = fmaxf(m, s2[kk]);
    e2[k] = expf(s2[k] - m);
  }
  __syncthreads();
  if (tid < 16) {
    float sum = 0.f;
    for (int k = 0; k < 16; ++k) sum += e1[k];
    const float a = e1[tid] / sum;
    for (int t = 0; t < T1; ++t) {
      float xv = (tid < IN2) ? X[(size_t)b * (T1 * IN2) + t * IN2 + tid] : ypb[t];
      x1h[((size_t)t * Bsz + b) * 16 + tid] = __float2bfloat16(a * xv);
    }
  } else if (tid < 16 + IN2) {
    const int k = tid - 16;
    float sum = 0.f;
    for (int kk = 0; kk < IN2; ++kk) sum += e2[kk];
    const float a = e2[k] / sum;
    for (int t = 0; t < T1; ++t)
      x2h[((size_t)t * Bsz + b) * 16 + k] =
          __float2bfloat16(a * X[(size_t)b * (T1 * IN2) + t * IN2 + k] * ypb[t]);
  } else if (tid == 31) {
    const bf16 z = __float2bfloat16(0.f);
    for (int t = 0; t < T1; ++t) x2h[((size_t)t * Bsz + b) * 16 + 15] = z;
  }
}

// v[dd] = sum_h dec_attn2_W[0,h] * dec_attn1_W[h, 4H+dd]
// Wave-per-output GEMV: grid 1024 x 64 threads, lane l sums 8 h's, shfl-reduce.
__global__ void prep_v_k(const float* __restrict__ A1W, const float* __restrict__ A2W,
                         float* __restrict__ v) {
  const int dd = blockIdx.x;      // 0..1023
  const int l = threadIdx.x;      // 0..63
  float acc = 0.f;
#pragma unroll
  for (int k = 0; k < 8; ++k) {
    const int h = l + 64 * k;
    acc += A2W[h] * A1W[(size_t)h * (6 * Hs) + 4 * Hs + dd];
  }
#pragma unroll
  for (int off = 32; off > 0; off >>= 1) acc += __shfl_down(acc, off);
  if (l == 0) v[dd] = acc;
}

// Decoder attention (step-invariant): softmax over t, context, y_tilde table.
__global__ void dec_ctx_k(const float* __restrict__ Xe, const float* __restrict__ v,
                          const float* __restrict__ yp, const float* __restrict__ fcW,
                          const float* __restrict__ fcb,
                          float* __restrict__ ctx, float* __restrict__ yt) {
  const int b = blockIdx.x;
  const int tid = threadIdx.x;  // 256
  const float* xb = Xe + (size_t)b * (T1 * 2 * Hs);
  float s[T1];
#pragma unroll
  for (int t = 0; t < T1; ++t) s[t] = 0.f;
  for (int dd = tid; dd < 2 * Hs; dd += 256) {
    const float vv = v[dd];
#pragma unroll
    for (int t = 0; t < T1; ++t) s[t] += xb[t * 2 * Hs + dd] * vv;
  }
  __shared__ float red[256];
  __shared__ float score[T1];
  for (int t = 0; t < T1; ++t) {
    red[tid] = s[t];
    __syncthreads();
    for (int off = 128; off > 0; off >>= 1) {
      if (tid < off) red[tid] += red[tid + off];
      __syncthreads();
    }
    if (tid == 0) score[t] = red[0];
    __syncthreads();
  }
  float mx = -1e30f;
#pragma unroll
  for (int t = 0; t < T1; ++t) mx = fmaxf(mx, score[t]);
  float e[T1];
  float sum = 0.f;
#pragma unroll
  for (int t = 0; t < T1; ++t) { e[t] = expf(score[t] - mx); sum += e[t]; }
  const float inv = 1.f / sum;
  float fcacc = 0.f;
  for (int dd = tid; dd < 2 * Hs; dd += 256) {
    float c = 0.f;
#pragma unroll
    for (int t = 0; t < T1; ++t) c += e[t] * xb[t * 2 * Hs + dd];
    c *= inv;
    ctx[(size_t)b * 2 * Hs + dd] = c;
    fcacc += c * fcW[dd];
  }
  red[tid] = fcacc;
  __syncthreads();
  for (int off = 128; off > 0; off >>= 1) {
    if (tid < off) red[tid] += red[tid + off];
    __syncthreads();
  }
  const float cf = red[0] + fcb[0];
  if (tid < T1) yt[(size_t)b * T1 + tid] = cf + yp[(size_t)b * T1 + tid] * fcW[2 * Hs];
}

__global__ void final_out_k(const float* __restrict__ dfin, const float* __restrict__ ctx,
                            const float* __restrict__ Wfin, const float* __restrict__ bfin,
                            float* __restrict__ out) {
  const int b = blockIdx.x;
  const int tid = threadIdx.x;  // 256
  float acc = 0.f;
  for (int jj = tid; jj < 2 * Hs; jj += 256) acc += dfin[(size_t)b * 2 * Hs + jj] * Wfin[jj];
  for (int jj = tid; jj < 2 * Hs; jj += 256) acc += ctx[(size_t)b * 2 * Hs + jj] * Wfin[2 * Hs + jj];
  __shared__ float red[256];
  red[tid] = acc;
  __syncthreads();
  for (int off = 128; off > 0; off >>= 1) {
    if (tid < off) red[tid] += red[tid + off];
    __syncthreads();
  }
  if (tid == 0) out[b] = red[0] + bfin[0];
}

extern "C" void kernel_launch(void* const* d_in, const int* in_sizes, int n_in,
                              void* d_out, int out_size, void* d_ws, size_t ws_size,
                              hipStream_t stream) {
  const float* X     = (const float*)d_in[0];
  const float* yp    = (const float*)d_in[1];
  const float* encW  = (const float*)d_in[2];
  const float* encb  = (const float*)d_in[3];
  const float* e0Wih = (const float*)d_in[4];
  const float* e0Whh = (const float*)d_in[5];
  const float* e0bih = (const float*)d_in[6];
  const float* e0bhh = (const float*)d_in[7];
  const float* e1Wih = (const float*)d_in[8];
  const float* e1Whh = (const float*)d_in[9];
  const float* e1bih = (const float*)d_in[10];
  const float* e1bhh = (const float*)d_in[11];
  const float* dA1W  = (const float*)d_in[12];
  const float* dA2W  = (const float*)d_in[14];
  const float* dWih  = (const float*)d_in[16];
  const float* dWhh  = (const float*)d_in[17];
  const float* dbih  = (const float*)d_in[18];
  const float* dbhh  = (const float*)d_in[19];
  const float* fcW   = (const float*)d_in[20];
  const float* fcb   = (const float*)d_in[21];
  const float* WfinW = (const float*)d_in[22];
  const float* Wfinb = (const float*)d_in[23];
  float* out = (float*)d_out;
  (void)in_sizes; (void)n_in; (void)out_size; (void)ws_size;

  char* wsb = (char*)d_ws;
  size_t off = 0;
  auto alloc = [&](size_t bytes) -> void* {
    void* p = wsb + off;
    off = (off + bytes + 255) & ~(size_t)255;
    return p;
  };
  const size_t BH  = (size_t)Bsz * Hs;
  const size_t BH2 = (size_t)Bsz * 2 * Hs;
  // ---- zero-init region (one memset per call) ----
  float* c1   = (float*)alloc(BH * 4);
  float* c2   = (float*)alloc(BH * 4);
  float* cdec = (float*)alloc(BH2 * 4);
  bf16* h1hi0 = (bf16*)alloc(BH * 2);
  bf16* h2hi0 = (bf16*)alloc(BH * 2);
  bf16* dhi0  = (bf16*)alloc(BH2 * 2);
  const size_t zero_bytes = off;
  // ---- rest ----
  bf16* h1hi1 = (bf16*)alloc(BH * 2);
  bf16* h2hi1 = (bf16*)alloc(BH * 2);
  bf16* dhi1  = (bf16*)alloc(BH2 * 2);
  bf16* W0hi  = (bf16*)alloc((size_t)2048 * 544 * 2);
  bf16* W0lo  = (bf16*)alloc((size_t)2048 * 544 * 2);
  bf16* W1hi  = (bf16*)alloc((size_t)2048 * 544 * 2);
  bf16* W1lo  = (bf16*)alloc((size_t)2048 * 544 * 2);
  bf16* Wdhi  = (bf16*)alloc((size_t)4096 * 1024 * 2);
  bf16* Wdlo  = (bf16*)alloc((size_t)4096 * 1024 * 2);
  float* bs0  = (float*)alloc(2048 * 4);
  float* bs1  = (float*)alloc(2048 * 4);
  float* bsd  = (float*)alloc(4096 * 4);
  float* wihp = (float*)alloc(4096 * 4);
  bf16* x1h   = (bf16*)alloc((size_t)T1 * Bsz * 16 * 2);
  bf16* x2h   = (bf16*)alloc((size_t)T1 * Bsz * 16 * 2);
  float* Xe   = (float*)alloc((size_t)Bsz * T1 * 2 * Hs * 4);
  float* dfp  = (float*)alloc(BH2 * 4);
  float* ctx  = (float*)alloc(BH2 * 4);
  float* vv   = (float*)alloc(2 * Hs * 4);
  float* yt   = (float*)alloc((size_t)Bsz * T1 * 4);

  hipMemsetAsync(d_ws, 0, zero_bytes, stream);

  build_w_k<<<(4 * Hs * (544 / 8) + 255) / 256, 256, 0, stream>>>(
      e0Whh, e0Wih, e0bih, e0bhh, W0hi, W0lo, bs0, nullptr, Hs, 16, 544);
  build_w_k<<<(4 * Hs * (544 / 8) + 255) / 256, 256, 0, stream>>>(
      e1Whh, e1Wih, e1bih, e1bhh, W1hi, W1lo, bs1, nullptr, Hs, 15, 544);
  build_w_k<<<(8 * Hs * (1024 / 8) + 255) / 256, 256, 0, stream>>>(
      dWhh, dWih, dbih, dbhh, Wdhi, Wdlo, bsd, wihp, 2 * Hs, 0, 1024);
  prep_attn_k<<<Bsz, 64, 0, stream>>>(X, yp, encW, encb, x1h, x2h);
  prep_v_k<<<2 * Hs, 64, 0, stream>>>(dA1W, dA2W, vv);

  // ---- encoder: 9 steps, both branches per launch ----
  bf16 *h1c = h1hi0, *h1n = h1hi1;
  bf16 *h2c = h2hi0, *h2n = h2hi1;
  for (int t = 0; t < T1; ++t) {
    GA a0{h1c, x1h + (size_t)t * Bsz * 16, W0hi, W0lo, bs0, nullptr, nullptr,
          c1, h1n, Xe + (size_t)t * 2 * Hs, T1 * 2 * Hs, 0};
    GA a1{h2c, x2h + (size_t)t * Bsz * 16, W1hi, W1lo, bs1, nullptr, nullptr,
          c2, h2n, Xe + (size_t)t * 2 * Hs + Hs, T1 * 2 * Hs, 0};
    dim3 grid((4 * Hs) / BNP, Bsz / BMT, 2);
    lstm2_k<Hs, 544, true, 2><<<grid, 256, 0, stream>>>(a0, a1);
    bf16* tp;
    tp = h1c; h1c = h1n; h1n = tp;
    tp = h2c; h2c = h2n; h2n = tp;
  }

  dec_ctx_k<<<Bsz, 256, 0, stream>>>(Xe, vv, yp, fcW, fcb, ctx, yt);

  // ---- decoder: 9 steps ----
  bf16 *dc = dhi0, *dn = dhi1;
  for (int t = 0; t < T1; ++t) {
    GA a0{dc, nullptr, Wdhi, Wdlo, bsd, wihp, yt + t,
          cdec, dn, (t == T1 - 1) ? dfp : nullptr, 2 * Hs, T1};
    dim3 grid((8 * Hs) / BNP, Bsz / BMT, 1);
    lstm2_k<2 * Hs, 1024, false, 1><<<grid, 256, 0, stream>>>(a0, a0);
    bf16* tp = dc; dc = dn; dn = tp;
  }

  final_out_k<<<Bsz, 256, 0, stream>>>(dfp, ctx, WfinW, Wfinb, out);
}